// Round 11
// baseline (136.259 us; speedup 1.0000x reference)
//
#include <hip/hip_runtime.h>
#include <math.h>

typedef __bf16 bf16;
typedef bf16 bf16x2 __attribute__((ext_vector_type(2)));
typedef bf16 bf16x4 __attribute__((ext_vector_type(4)));
typedef bf16 bf16x8 __attribute__((ext_vector_type(8)));
typedef float f32x4 __attribute__((ext_vector_type(4)));

constexpr int CENTER = 31;

static __device__ __forceinline__ unsigned short f2bf_bits(float f) {
    bf16 b = (bf16)f;
    return __builtin_bit_cast(unsigned short, b);
}

// =====================================================================
// Kernel 0: one-shot fp32 -> bf16 conversions (R9-proven).
//   hb  [b][pos][d]   row-major hidden bf16 (qkproj A)
//   htb [b][d][pos]   transposed hidden bf16 (attn V operand)
//   Wqb/Wkb [o][d]    bf16 weights
//   Wvp               MFMA-B-packed Wv (out_proj B)
// grid = 128 blocks (b, 64-pos chunk), block 256.
// =====================================================================
__global__ __launch_bounds__(256)
void prep_kernel(const float* __restrict__ hid,
                 const float* __restrict__ Wq, const float* __restrict__ Wk,
                 const float* __restrict__ Wv,
                 bf16* __restrict__ hb, bf16* __restrict__ htb,
                 bf16* __restrict__ Wqb, bf16* __restrict__ Wkb,
                 bf16* __restrict__ Wvp)
{
    __shared__ __attribute__((aligned(16))) bf16 hs[64][72];

    const int t   = threadIdx.x;
    const int blk = blockIdx.x;
    const int b   = blk >> 4, kc = blk & 15;

    {
        int row = t >> 2, c4 = (t & 3) * 16;
        const float4* src = (const float4*)(hid + ((size_t)b * 1024 + kc * 64 + row) * 64 + c4);
        bf16 tmp[16];
        #pragma unroll
        for (int u = 0; u < 4; ++u) {
            float4 v = src[u];
            tmp[4*u+0] = (bf16)v.x; tmp[4*u+1] = (bf16)v.y;
            tmp[4*u+2] = (bf16)v.z; tmp[4*u+3] = (bf16)v.w;
        }
        *(int4*)&hs[row][c4]     = ((int4*)tmp)[0];
        *(int4*)&hs[row][c4 + 8] = ((int4*)tmp)[1];
        bf16* hdst = hb + ((size_t)b * 1024 + kc * 64 + row) * 64 + c4;
        *(int4*)hdst       = ((int4*)tmp)[0];
        *(int4*)(hdst + 8) = ((int4*)tmp)[1];
    }

    {
        int idx = blk * 256 + t;
        if (idx < 8192) {
            float4 vq = ((const float4*)Wq)[idx];
            float4 vk = ((const float4*)Wk)[idx];
            float4 vv = ((const float4*)Wv)[idx];
            ushort4 pq, pk2, pv;
            pq.x = f2bf_bits(vq.x); pq.y = f2bf_bits(vq.y); pq.z = f2bf_bits(vq.z); pq.w = f2bf_bits(vq.w);
            pk2.x = f2bf_bits(vk.x); pk2.y = f2bf_bits(vk.y); pk2.z = f2bf_bits(vk.z); pk2.w = f2bf_bits(vk.w);
            pv.x = f2bf_bits(vv.x); pv.y = f2bf_bits(vv.y); pv.z = f2bf_bits(vv.z); pv.w = f2bf_bits(vv.w);
            ((ushort4*)Wqb)[idx] = pq;
            ((ushort4*)Wkb)[idx] = pk2;
            int c = idx >> 7, o4 = (idx & 127) * 4;
            size_t dst = (size_t)((c >> 4) * 16 + (o4 >> 5)) * 512 + (c & 15) * 32 + (o4 & 31);
            *(ushort4*)(Wvp + dst) = pv;
        }
    }
    __syncthreads();

    {
        int d = t >> 2, p0 = (t & 3) * 16;
        ushort tmp[16];
        #pragma unroll
        for (int i = 0; i < 16; ++i)
            tmp[i] = __builtin_bit_cast(unsigned short, hs[p0 + i][d]);
        bf16* dst = htb + ((size_t)b * 64 + d) * 1024 + kc * 64 + p0;
        *(int4*)dst       = ((int4*)tmp)[0];
        *(int4*)(dst + 8) = ((int4*)tmp)[1];
    }
}

// =====================================================================
// Kernel 1: Q/K projection GEMM via MFMA, all-bf16 (R7 math) with
// COALESCED epilogue: C-layout acc -> Bqs scratch (free after its MFMA
// phase) -> row-major int4 stores (was 128 scalar 2B stores/thread).
// grid = (64 pos-tiles x 4 out-tiles), block 256.
// =====================================================================
__global__ __launch_bounds__(256)
void qkproj_kernel(const bf16* __restrict__ hb,
                   const bf16* __restrict__ Wqb, const float* __restrict__ bq,
                   const bf16* __restrict__ Wkb, const float* __restrict__ bk,
                   bf16* __restrict__ qb, bf16* __restrict__ kb)
{
    __shared__ __attribute__((aligned(16))) bf16 As[128][72];
    __shared__ __attribute__((aligned(16))) bf16 Bqs[128][72];   // B(q) then epilogue scratch
    __shared__ __attribute__((aligned(16))) bf16 Bks[128][72];

    const int t  = threadIdx.x;
    const int pt = blockIdx.x;
    const int ot = blockIdx.y;
    const int p0 = pt * 128;
    const int b  = p0 >> 10;

    {
        int row = t >> 1, ch = (t & 1) * 32;
        const int4* asrc = (const int4*)(hb + (size_t)(p0 + row) * 64 + ch);
        const int4* qsrc = (const int4*)(Wqb + (size_t)(ot * 128 + row) * 64 + ch);
        const int4* ksrc = (const int4*)(Wkb + (size_t)(ot * 128 + row) * 64 + ch);
        #pragma unroll
        for (int u = 0; u < 4; ++u) {
            *(int4*)&As[row][ch + u * 8]  = asrc[u];
            *(int4*)&Bqs[row][ch + u * 8] = qsrc[u];
            *(int4*)&Bks[row][ch + u * 8] = ksrc[u];
        }
    }
    __syncthreads();

    const int w = t >> 6, ln = t & 63, l15 = ln & 15, quad = ln >> 4;
    const int erow = t >> 1;          // epilogue: output row (pos within tile)
    const int ec0  = (t & 1) * 32;    // epilogue: d-offset

    bf16x8 a[2][2];
    #pragma unroll
    for (int mt = 0; mt < 2; ++mt) {
        a[mt][0] = *(const bf16x8*)&As[w * 32 + mt * 16 + l15][quad * 8];
        a[mt][1] = *(const bf16x8*)&As[w * 32 + mt * 16 + l15][32 + quad * 8];
    }

    const f32x4 z4 = {0.f, 0.f, 0.f, 0.f};

    for (int z = 0; z < 2; ++z) {
        const bf16 (* __restrict__ Bs)[72] = z ? Bks : Bqs;
        const float* bias = z ? bk : bq;
        bf16* outp        = z ? kb : qb;
        const float scale = z ? 1.0f : 0.125f;

        f32x4 acc[2][8];
        #pragma unroll
        for (int mt = 0; mt < 2; ++mt)
            #pragma unroll
            for (int nt = 0; nt < 8; ++nt) acc[mt][nt] = z4;

        #pragma unroll
        for (int nt = 0; nt < 8; ++nt) {
            bf16x8 b0 = *(const bf16x8*)&Bs[nt * 16 + l15][quad * 8];
            bf16x8 b1 = *(const bf16x8*)&Bs[nt * 16 + l15][32 + quad * 8];
            #pragma unroll
            for (int mt = 0; mt < 2; ++mt) {
                acc[mt][nt] = __builtin_amdgcn_mfma_f32_16x16x32_bf16(a[mt][0], b0, acc[mt][nt], 0, 0, 0);
                acc[mt][nt] = __builtin_amdgcn_mfma_f32_16x16x32_bf16(a[mt][1], b1, acc[mt][nt], 0, 0, 0);
            }
        }

        // epilogue: two 64-o halves (one head each) through Bqs scratch
        for (int half = 0; half < 2; ++half) {
            __syncthreads();   // scratch free (MFMA reads / prior stores done)
            #pragma unroll
            for (int nt2 = 0; nt2 < 4; ++nt2) {
                int nt = half * 4 + nt2;
                float bv = bias[ot * 128 + nt * 16 + l15];
                #pragma unroll
                for (int mt = 0; mt < 2; ++mt)
                    #pragma unroll
                    for (int r = 0; r < 4; ++r)
                        Bqs[w * 32 + mt * 16 + quad * 4 + r][nt2 * 16 + l15] =
                            (bf16)((acc[mt][nt][r] + bv) * scale);
            }
            __syncthreads();
            int hh = ot * 2 + half;
            const int4* srow = (const int4*)&Bqs[erow][ec0];
            bf16* dst = outp + (((size_t)b * 8 + hh) * 1024 + (p0 & 1023) + erow) * 64 + ec0;
            #pragma unroll
            for (int u = 0; u < 4; ++u) ((int4*)dst)[u] = srow[u];
        }
    }
}

// =====================================================================
// Kernel 2: positional-bias precompute via MFMA (proven, unchanged).
// =====================================================================
__global__ __launch_bounds__(256)
void bias_kernel(const bf16* __restrict__ qb,
                 const float* __restrict__ row_emb, const float* __restrict__ col_emb,
                 bf16* __restrict__ rowbias, bf16* __restrict__ colbias)
{
    __shared__ __attribute__((aligned(16))) bf16 embRs[63][40];
    __shared__ __attribute__((aligned(16))) bf16 embCs[63][40];

    const int t  = threadIdx.x;
    const int bh = blockIdx.x;
    const int sg = blockIdx.y;

    for (int i = t; i < 2016; i += 256) embRs[i >> 5][i & 31] = (bf16)row_emb[i];
    for (int i = t; i < 2016; i += 256) embCs[i >> 5][i & 31] = (bf16)col_emb[i];
    __syncthreads();

    const int w = t >> 6, ln = t & 63, l15 = ln & 15, quad = ln >> 4;

    #pragma unroll
    for (int u = 0; u < 4; ++u) {
        int s = sg * 16 + u * 4 + w;
        bool cm = s >= 32;
        int ij = cm ? s - 32 : s;

        bf16x8 a[2];
        #pragma unroll
        for (int mt = 0; mt < 2; ++mt) {
            const bf16* ap = cm
                ? qb + ((size_t)bh * 1024 + (mt * 16 + l15) * 32 + ij) * 64 + 32 + quad * 8
                : qb + ((size_t)bh * 1024 + ij * 32 + mt * 16 + l15) * 64 + quad * 8;
            a[mt] = *(const bf16x8*)ap;
        }
        bf16* ob = cm ? colbias : rowbias;

        #pragma unroll
        for (int nt = 0; nt < 2; ++nt) {
            int erow = nt * 16 + l15 + CENTER - ij;
            bf16x8 bfrag = cm ? *(const bf16x8*)&embCs[erow][quad * 8]
                              : *(const bf16x8*)&embRs[erow][quad * 8];
            #pragma unroll
            for (int mt = 0; mt < 2; ++mt) {
                f32x4 c = {0.f, 0.f, 0.f, 0.f};
                c = __builtin_amdgcn_mfma_f32_16x16x32_bf16(a[mt], bfrag, c, 0, 0, 0);
                #pragma unroll
                for (int r = 0; r < 4; ++r) {
                    int ql = mt * 16 + quad * 4 + r;
                    int qrow = cm ? ql * 32 + ij : ij * 32 + ql;
                    ob[((size_t)bh * 1024 + qrow) * 32 + nt * 16 + l15] = (bf16)c[r];
                }
            }
        }
    }
}

// =====================================================================
// Kernel 3: MFMA flash attention, TRANSPOSED dataflow (R4/R7/R9 proven,
// byte-identical revert).
// grid (8 q-tiles of 128, 64 bh), block 256 (4 waves x 32 q).
// =====================================================================
__global__ __launch_bounds__(256, 2)
void attn_kernel(const bf16* __restrict__ qb, const bf16* __restrict__ kb,
                 const bf16* __restrict__ htb,
                 const bf16* __restrict__ rowbias, const bf16* __restrict__ colbias,
                 bf16* __restrict__ mixedb)
{
    __shared__ __attribute__((aligned(16))) bf16 Ks[64][72];
    __shared__ __attribute__((aligned(16))) bf16 Hts[64][72];
    __shared__ __attribute__((aligned(16))) bf16 Pp[4][32][72];

    const int t  = threadIdx.x;
    const int qt = blockIdx.x;
    const int bh = blockIdx.y;
    const int b  = bh >> 3, h = bh & 7;
    const int q0 = qt * 128;
    const int w = t >> 6, ln = t & 63, l15 = ln & 15, quad = ln >> 4;

    bf16x8 bq_[2][2];
    float  cbv[2][2][4];
    const bf16* rbp[2];
    #pragma unroll
    for (int mt = 0; mt < 2; ++mt) {
        int qrow = q0 + w * 32 + mt * 16 + l15;
        const bf16* qp = qb + ((size_t)bh * 1024 + qrow) * 64;
        bq_[mt][0] = *(const bf16x8*)(qp + quad * 8);
        bq_[mt][1] = *(const bf16x8*)(qp + 32 + quad * 8);
        #pragma unroll
        for (int par = 0; par < 2; ++par) {
            bf16x4 cv = *(const bf16x4*)(colbias + ((size_t)bh * 1024 + qrow) * 32 + par * 16 + quad * 4);
            #pragma unroll
            for (int r = 0; r < 4; ++r) cbv[mt][par][r] = (float)cv[r];
        }
        rbp[mt] = rowbias + ((size_t)bh * 1024 + qrow) * 32;
    }

    const f32x4 z4 = {0.f, 0.f, 0.f, 0.f};
    f32x4 oacc[2][4];
    float lsum[2] = {0.f, 0.f};
    #pragma unroll
    for (int mt = 0; mt < 2; ++mt)
        #pragma unroll
        for (int dt = 0; dt < 4; ++dt) oacc[mt][dt] = z4;

    bf16* Pw = &Pp[w][0][0];
    const bf16* kcbase = kb + (size_t)bh * 1024 * 64;
    const bf16* hcbase = htb + (size_t)b * 64 * 1024;

    for (int kc = 0; kc < 16; ++kc) {
        __syncthreads();
        {
            int row = t >> 2, c = (t & 3) << 4;
            const bf16* ksrc = kcbase + (size_t)(kc * 64 + row) * 64 + c;
            *(int4*)&Ks[row][c]     = *(const int4*)ksrc;
            *(int4*)&Ks[row][c + 8] = *(const int4*)(ksrc + 8);
            const bf16* hsrc = hcbase + (size_t)row * 1024 + kc * 64 + c;
            *(int4*)&Hts[row][c]     = *(const int4*)hsrc;
            *(int4*)&Hts[row][c + 8] = *(const int4*)(hsrc + 8);
        }
        float rb[2][2];
        #pragma unroll
        for (int mt = 0; mt < 2; ++mt) {
            bf16x2 rv = *(const bf16x2*)(rbp[mt] + kc * 2);
            rb[mt][0] = (float)rv[0]; rb[mt][1] = (float)rv[1];
        }
        __syncthreads();

        f32x4 sf[2][4];
        #pragma unroll
        for (int mt = 0; mt < 2; ++mt)
            #pragma unroll
            for (int kt = 0; kt < 4; ++kt) sf[mt][kt] = z4;
        #pragma unroll
        for (int kt = 0; kt < 4; ++kt) {
            bf16x8 aK0 = *(const bf16x8*)&Ks[kt * 16 + l15][quad * 8];
            bf16x8 aK1 = *(const bf16x8*)&Ks[kt * 16 + l15][32 + quad * 8];
            #pragma unroll
            for (int mt = 0; mt < 2; ++mt) {
                sf[mt][kt] = __builtin_amdgcn_mfma_f32_16x16x32_bf16(aK0, bq_[mt][0], sf[mt][kt], 0, 0, 0);
                sf[mt][kt] = __builtin_amdgcn_mfma_f32_16x16x32_bf16(aK1, bq_[mt][1], sf[mt][kt], 0, 0, 0);
            }
        }

        #pragma unroll
        for (int mt = 0; mt < 2; ++mt)
            #pragma unroll
            for (int kt = 0; kt < 4; ++kt) {
                float rbv = rb[mt][kt >> 1];
                ushort4 pk;
                float p0 = __expf(sf[mt][kt][0] + rbv + cbv[mt][kt & 1][0]);
                float p1 = __expf(sf[mt][kt][1] + rbv + cbv[mt][kt & 1][1]);
                float p2 = __expf(sf[mt][kt][2] + rbv + cbv[mt][kt & 1][2]);
                float p3 = __expf(sf[mt][kt][3] + rbv + cbv[mt][kt & 1][3]);
                lsum[mt] += (p0 + p1) + (p2 + p3);
                pk.x = f2bf_bits(p0); pk.y = f2bf_bits(p1);
                pk.z = f2bf_bits(p2); pk.w = f2bf_bits(p3);
                *(ushort4*)&Pw[(mt * 16 + l15) * 72 + kt * 16 + quad * 4] = pk;
            }

        bf16x8 bp[2][2];
        #pragma unroll
        for (int mt = 0; mt < 2; ++mt) {
            bp[mt][0] = *(const bf16x8*)&Pw[(mt * 16 + l15) * 72 + quad * 8];
            bp[mt][1] = *(const bf16x8*)&Pw[(mt * 16 + l15) * 72 + 32 + quad * 8];
        }
        #pragma unroll
        for (int dt = 0; dt < 4; ++dt) {
            bf16x8 aH0 = *(const bf16x8*)&Hts[dt * 16 + l15][quad * 8];
            bf16x8 aH1 = *(const bf16x8*)&Hts[dt * 16 + l15][32 + quad * 8];
            #pragma unroll
            for (int mt = 0; mt < 2; ++mt) {
                oacc[mt][dt] = __builtin_amdgcn_mfma_f32_16x16x32_bf16(aH0, bp[mt][0], oacc[mt][dt], 0, 0, 0);
                oacc[mt][dt] = __builtin_amdgcn_mfma_f32_16x16x32_bf16(aH1, bp[mt][1], oacc[mt][dt], 0, 0, 0);
            }
        }
    }

    float inv[2];
    #pragma unroll
    for (int mt = 0; mt < 2; ++mt) {
        float v = lsum[mt];
        v += __shfl_xor(v, 16);
        v += __shfl_xor(v, 32);
        inv[mt] = 1.0f / v;
    }
    #pragma unroll
    for (int mt = 0; mt < 2; ++mt) {
        int pos = q0 + w * 32 + mt * 16 + l15;
        bf16* mb = mixedb + ((size_t)b * 1024 + pos) * 512 + h * 64;
        #pragma unroll
        for (int dt = 0; dt < 4; ++dt) {
            ushort4 pk;
            pk.x = f2bf_bits(oacc[mt][dt][0] * inv[mt]);
            pk.y = f2bf_bits(oacc[mt][dt][1] * inv[mt]);
            pk.z = f2bf_bits(oacc[mt][dt][2] * inv[mt]);
            pk.w = f2bf_bits(oacc[mt][dt][3] * inv[mt]);
            *(ushort4*)(mb + dt * 16 + quad * 4) = pk;
        }
    }
}

// =====================================================================
// Kernel 4: output projection via MFMA — zero LDS, zero barriers (proven).
// grid 256 blocks (32 pos), block 256 (4 waves; wave w = col-tile).
// =====================================================================
__global__ __launch_bounds__(256)
void out_proj_kernel(const bf16* __restrict__ mixedb,
                     const bf16* __restrict__ Wvp, const float* __restrict__ bv,
                     float* __restrict__ out)
{
    const int t  = threadIdx.x;
    const int p0 = blockIdx.x * 32;
    const int w = t >> 6, ln = t & 63, l15 = ln & 15, quad = ln >> 4;

    float bvv = bv[w * 16 + l15];
    f32x4 acc[2] = {(f32x4){bvv, bvv, bvv, bvv}, (f32x4){bvv, bvv, bvv, bvv}};

    const bf16* arow0 = mixedb + (size_t)(p0 + l15) * 512 + quad * 8;
    const bf16* arow1 = mixedb + (size_t)(p0 + 16 + l15) * 512 + quad * 8;
    const bf16* bbase = Wvp + (size_t)w * 16 * 512 + l15 * 32 + quad * 8;

    #pragma unroll
    for (int kc = 0; kc < 16; ++kc) {
        bf16x8 a0 = *(const bf16x8*)(arow0 + kc * 32);
        bf16x8 a1 = *(const bf16x8*)(arow1 + kc * 32);
        bf16x8 bfrag = *(const bf16x8*)(bbase + kc * 512);
        acc[0] = __builtin_amdgcn_mfma_f32_16x16x32_bf16(a0, bfrag, acc[0], 0, 0, 0);
        acc[1] = __builtin_amdgcn_mfma_f32_16x16x32_bf16(a1, bfrag, acc[1], 0, 0, 0);
    }

    #pragma unroll
    for (int mt = 0; mt < 2; ++mt)
        #pragma unroll
        for (int r = 0; r < 4; ++r)
            out[(size_t)(p0 + mt * 16 + quad * 4 + r) * 64 + w * 16 + l15] = acc[mt][r];
}

// =====================================================================
extern "C" void kernel_launch(void* const* d_in, const int* in_sizes, int n_in,
                              void* d_out, int out_size, void* d_ws, size_t ws_size,
                              hipStream_t stream)
{
    const float* hid     = (const float*)d_in[0];
    const float* row_emb = (const float*)d_in[1];
    const float* col_emb = (const float*)d_in[2];
    const float* Wq      = (const float*)d_in[3];
    const float* bq      = (const float*)d_in[4];
    const float* Wk      = (const float*)d_in[5];
    const float* bk      = (const float*)d_in[6];
    const float* Wv      = (const float*)d_in[7];
    const float* bv      = (const float*)d_in[8];
    float* out = (float*)d_out;

    bf16* qb      = (bf16*)d_ws;
    bf16* kb      = qb + (size_t)64 * 1024 * 64;
    bf16* htb     = kb + (size_t)64 * 1024 * 64;
    bf16* rowbias = htb + (size_t)8 * 64 * 1024;
    bf16* colbias = rowbias + (size_t)64 * 1024 * 32;
    bf16* mixedb  = colbias + (size_t)64 * 1024 * 32;
    bf16* hb      = mixedb + (size_t)8 * 1024 * 512;
    bf16* Wqb     = hb + (size_t)8 * 1024 * 64;
    bf16* Wkb     = Wqb + (size_t)512 * 64;
    bf16* Wvp     = Wkb + (size_t)512 * 64;

    prep_kernel<<<128, 256, 0, stream>>>(hid, Wq, Wk, Wv, hb, htb, Wqb, Wkb, Wvp);
    qkproj_kernel<<<dim3(64, 4), 256, 0, stream>>>(hb, Wqb, bq, Wkb, bk, qb, kb);
    bias_kernel<<<dim3(64, 4), 256, 0, stream>>>(qb, row_emb, col_emb, rowbias, colbias);
    attn_kernel<<<dim3(8, 64), 256, 0, stream>>>(qb, kb, htb, rowbias, colbias, mixedb);
    out_proj_kernel<<<256, 256, 0, stream>>>(mixedb, Wvp, bv, out);
}

// Round 12
// 129.597 us; speedup vs baseline: 1.0514x; 1.0514x over previous
//
#include <hip/hip_runtime.h>
#include <math.h>

typedef __bf16 bf16;
typedef bf16 bf16x2 __attribute__((ext_vector_type(2)));
typedef bf16 bf16x4 __attribute__((ext_vector_type(4)));
typedef bf16 bf16x8 __attribute__((ext_vector_type(8)));
typedef float f32x4 __attribute__((ext_vector_type(4)));

constexpr int CENTER = 31;

static __device__ __forceinline__ unsigned short f2bf_bits(float f) {
    bf16 b = (bf16)f;
    return __builtin_bit_cast(unsigned short, b);
}

// =====================================================================
// FINAL (R9-verified best, 130.18 us): revert of the R10/R11 experiments.
// Kernel 0: one-shot fp32 -> bf16 conversions.
//   hb  [b][pos][d]   row-major hidden bf16 (qkproj A)
//   htb [b][d][pos]   transposed hidden bf16 (attn V operand)
//   Wqb/Wkb [o][d]    bf16 weights
//   Wvp               MFMA-B-packed Wv (out_proj B)
// grid = 128 blocks (b, 64-pos chunk), block 256.
// =====================================================================
__global__ __launch_bounds__(256)
void prep_kernel(const float* __restrict__ hid,
                 const float* __restrict__ Wq, const float* __restrict__ Wk,
                 const float* __restrict__ Wv,
                 bf16* __restrict__ hb, bf16* __restrict__ htb,
                 bf16* __restrict__ Wqb, bf16* __restrict__ Wkb,
                 bf16* __restrict__ Wvp)
{
    __shared__ __attribute__((aligned(16))) bf16 hs[64][72];

    const int t   = threadIdx.x;
    const int blk = blockIdx.x;
    const int b   = blk >> 4, kc = blk & 15;

    {
        int row = t >> 2, c4 = (t & 3) * 16;
        const float4* src = (const float4*)(hid + ((size_t)b * 1024 + kc * 64 + row) * 64 + c4);
        bf16 tmp[16];
        #pragma unroll
        for (int u = 0; u < 4; ++u) {
            float4 v = src[u];
            tmp[4*u+0] = (bf16)v.x; tmp[4*u+1] = (bf16)v.y;
            tmp[4*u+2] = (bf16)v.z; tmp[4*u+3] = (bf16)v.w;
        }
        *(int4*)&hs[row][c4]     = ((int4*)tmp)[0];
        *(int4*)&hs[row][c4 + 8] = ((int4*)tmp)[1];
        bf16* hdst = hb + ((size_t)b * 1024 + kc * 64 + row) * 64 + c4;
        *(int4*)hdst       = ((int4*)tmp)[0];
        *(int4*)(hdst + 8) = ((int4*)tmp)[1];
    }

    {
        int idx = blk * 256 + t;
        if (idx < 8192) {
            float4 vq = ((const float4*)Wq)[idx];
            float4 vk = ((const float4*)Wk)[idx];
            float4 vv = ((const float4*)Wv)[idx];
            ushort4 pq, pk2, pv;
            pq.x = f2bf_bits(vq.x); pq.y = f2bf_bits(vq.y); pq.z = f2bf_bits(vq.z); pq.w = f2bf_bits(vq.w);
            pk2.x = f2bf_bits(vk.x); pk2.y = f2bf_bits(vk.y); pk2.z = f2bf_bits(vk.z); pk2.w = f2bf_bits(vk.w);
            pv.x = f2bf_bits(vv.x); pv.y = f2bf_bits(vv.y); pv.z = f2bf_bits(vv.z); pv.w = f2bf_bits(vv.w);
            ((ushort4*)Wqb)[idx] = pq;
            ((ushort4*)Wkb)[idx] = pk2;
            int c = idx >> 7, o4 = (idx & 127) * 4;
            size_t dst = (size_t)((c >> 4) * 16 + (o4 >> 5)) * 512 + (c & 15) * 32 + (o4 & 31);
            *(ushort4*)(Wvp + dst) = pv;
        }
    }
    __syncthreads();

    {
        int d = t >> 2, p0 = (t & 3) * 16;
        ushort tmp[16];
        #pragma unroll
        for (int i = 0; i < 16; ++i)
            tmp[i] = __builtin_bit_cast(unsigned short, hs[p0 + i][d]);
        bf16* dst = htb + ((size_t)b * 64 + d) * 1024 + kc * 64 + p0;
        *(int4*)dst       = ((int4*)tmp)[0];
        *(int4*)(dst + 8) = ((int4*)tmp)[1];
    }
}

// =====================================================================
// Kernel 1: Q/K projection GEMM via MFMA, all-bf16 (R7-proven).
// grid = (64 pos-tiles x 4 out-tiles), block 256.
// =====================================================================
__global__ __launch_bounds__(256)
void qkproj_kernel(const bf16* __restrict__ hb,
                   const bf16* __restrict__ Wqb, const float* __restrict__ bq,
                   const bf16* __restrict__ Wkb, const float* __restrict__ bk,
                   bf16* __restrict__ qb, bf16* __restrict__ kb)
{
    __shared__ __attribute__((aligned(16))) bf16 As[128][72];
    __shared__ __attribute__((aligned(16))) bf16 Bqs[128][72];
    __shared__ __attribute__((aligned(16))) bf16 Bks[128][72];

    const int t  = threadIdx.x;
    const int pt = blockIdx.x;
    const int ot = blockIdx.y;
    const int p0 = pt * 128;
    const int b  = p0 >> 10;

    {
        int row = t >> 1, ch = (t & 1) * 32;
        const int4* asrc = (const int4*)(hb + (size_t)(p0 + row) * 64 + ch);
        const int4* qsrc = (const int4*)(Wqb + (size_t)(ot * 128 + row) * 64 + ch);
        const int4* ksrc = (const int4*)(Wkb + (size_t)(ot * 128 + row) * 64 + ch);
        #pragma unroll
        for (int u = 0; u < 4; ++u) {
            *(int4*)&As[row][ch + u * 8]  = asrc[u];
            *(int4*)&Bqs[row][ch + u * 8] = qsrc[u];
            *(int4*)&Bks[row][ch + u * 8] = ksrc[u];
        }
    }
    __syncthreads();

    const int w = t >> 6, ln = t & 63, l15 = ln & 15, quad = ln >> 4;

    bf16x8 a[2][2];
    #pragma unroll
    for (int mt = 0; mt < 2; ++mt) {
        a[mt][0] = *(const bf16x8*)&As[w * 32 + mt * 16 + l15][quad * 8];
        a[mt][1] = *(const bf16x8*)&As[w * 32 + mt * 16 + l15][32 + quad * 8];
    }

    const f32x4 z4 = {0.f, 0.f, 0.f, 0.f};

    for (int z = 0; z < 2; ++z) {
        const bf16 (* __restrict__ Bs)[72] = z ? Bks : Bqs;
        const float* bias = z ? bk : bq;
        bf16* outp        = z ? kb : qb;
        const float scale = z ? 1.0f : 0.125f;

        f32x4 acc[2][8];
        #pragma unroll
        for (int mt = 0; mt < 2; ++mt)
            #pragma unroll
            for (int nt = 0; nt < 8; ++nt) acc[mt][nt] = z4;

        #pragma unroll
        for (int nt = 0; nt < 8; ++nt) {
            bf16x8 b0 = *(const bf16x8*)&Bs[nt * 16 + l15][quad * 8];
            bf16x8 b1 = *(const bf16x8*)&Bs[nt * 16 + l15][32 + quad * 8];
            #pragma unroll
            for (int mt = 0; mt < 2; ++mt) {
                acc[mt][nt] = __builtin_amdgcn_mfma_f32_16x16x32_bf16(a[mt][0], b0, acc[mt][nt], 0, 0, 0);
                acc[mt][nt] = __builtin_amdgcn_mfma_f32_16x16x32_bf16(a[mt][1], b1, acc[mt][nt], 0, 0, 0);
            }
        }

        #pragma unroll
        for (int nt = 0; nt < 8; ++nt) {
            int o = ot * 128 + nt * 16 + l15;
            float bv = bias[o];
            int hh = o >> 6, d = o & 63;
            #pragma unroll
            for (int mt = 0; mt < 2; ++mt)
                #pragma unroll
                for (int r = 0; r < 4; ++r) {
                    int pos = (p0 & 1023) + w * 32 + mt * 16 + quad * 4 + r;
                    float val = (acc[mt][nt][r] + bv) * scale;
                    outp[(((size_t)b * 8 + hh) * 1024 + pos) * 64 + d] = (bf16)val;
                }
        }
    }
}

// =====================================================================
// Kernel 2: positional-bias precompute via MFMA (proven, unchanged).
// =====================================================================
__global__ __launch_bounds__(256)
void bias_kernel(const bf16* __restrict__ qb,
                 const float* __restrict__ row_emb, const float* __restrict__ col_emb,
                 bf16* __restrict__ rowbias, bf16* __restrict__ colbias)
{
    __shared__ __attribute__((aligned(16))) bf16 embRs[63][40];
    __shared__ __attribute__((aligned(16))) bf16 embCs[63][40];

    const int t  = threadIdx.x;
    const int bh = blockIdx.x;
    const int sg = blockIdx.y;

    for (int i = t; i < 2016; i += 256) embRs[i >> 5][i & 31] = (bf16)row_emb[i];
    for (int i = t; i < 2016; i += 256) embCs[i >> 5][i & 31] = (bf16)col_emb[i];
    __syncthreads();

    const int w = t >> 6, ln = t & 63, l15 = ln & 15, quad = ln >> 4;

    #pragma unroll
    for (int u = 0; u < 4; ++u) {
        int s = sg * 16 + u * 4 + w;
        bool cm = s >= 32;
        int ij = cm ? s - 32 : s;

        bf16x8 a[2];
        #pragma unroll
        for (int mt = 0; mt < 2; ++mt) {
            const bf16* ap = cm
                ? qb + ((size_t)bh * 1024 + (mt * 16 + l15) * 32 + ij) * 64 + 32 + quad * 8
                : qb + ((size_t)bh * 1024 + ij * 32 + mt * 16 + l15) * 64 + quad * 8;
            a[mt] = *(const bf16x8*)ap;
        }
        bf16* ob = cm ? colbias : rowbias;

        #pragma unroll
        for (int nt = 0; nt < 2; ++nt) {
            int erow = nt * 16 + l15 + CENTER - ij;
            bf16x8 bfrag = cm ? *(const bf16x8*)&embCs[erow][quad * 8]
                              : *(const bf16x8*)&embRs[erow][quad * 8];
            #pragma unroll
            for (int mt = 0; mt < 2; ++mt) {
                f32x4 c = {0.f, 0.f, 0.f, 0.f};
                c = __builtin_amdgcn_mfma_f32_16x16x32_bf16(a[mt], bfrag, c, 0, 0, 0);
                #pragma unroll
                for (int r = 0; r < 4; ++r) {
                    int ql = mt * 16 + quad * 4 + r;
                    int qrow = cm ? ql * 32 + ij : ij * 32 + ql;
                    ob[((size_t)bh * 1024 + qrow) * 32 + nt * 16 + l15] = (bf16)c[r];
                }
            }
        }
    }
}

// =====================================================================
// Kernel 3: MFMA flash attention, TRANSPOSED dataflow (R4/R7/R9 proven).
//   S^T = K·Q^T; P row-per-q in LDS; O^T = H^T·P^T; bf16 mixed out.
// grid (8 q-tiles of 128, 64 bh), block 256 (4 waves x 32 q).
// =====================================================================
__global__ __launch_bounds__(256, 2)
void attn_kernel(const bf16* __restrict__ qb, const bf16* __restrict__ kb,
                 const bf16* __restrict__ htb,
                 const bf16* __restrict__ rowbias, const bf16* __restrict__ colbias,
                 bf16* __restrict__ mixedb)
{
    __shared__ __attribute__((aligned(16))) bf16 Ks[64][72];
    __shared__ __attribute__((aligned(16))) bf16 Hts[64][72];
    __shared__ __attribute__((aligned(16))) bf16 Pp[4][32][72];

    const int t  = threadIdx.x;
    const int qt = blockIdx.x;
    const int bh = blockIdx.y;
    const int b  = bh >> 3, h = bh & 7;
    const int q0 = qt * 128;
    const int w = t >> 6, ln = t & 63, l15 = ln & 15, quad = ln >> 4;

    bf16x8 bq_[2][2];
    float  cbv[2][2][4];
    const bf16* rbp[2];
    #pragma unroll
    for (int mt = 0; mt < 2; ++mt) {
        int qrow = q0 + w * 32 + mt * 16 + l15;
        const bf16* qp = qb + ((size_t)bh * 1024 + qrow) * 64;
        bq_[mt][0] = *(const bf16x8*)(qp + quad * 8);
        bq_[mt][1] = *(const bf16x8*)(qp + 32 + quad * 8);
        #pragma unroll
        for (int par = 0; par < 2; ++par) {
            bf16x4 cv = *(const bf16x4*)(colbias + ((size_t)bh * 1024 + qrow) * 32 + par * 16 + quad * 4);
            #pragma unroll
            for (int r = 0; r < 4; ++r) cbv[mt][par][r] = (float)cv[r];
        }
        rbp[mt] = rowbias + ((size_t)bh * 1024 + qrow) * 32;
    }

    const f32x4 z4 = {0.f, 0.f, 0.f, 0.f};
    f32x4 oacc[2][4];
    float lsum[2] = {0.f, 0.f};
    #pragma unroll
    for (int mt = 0; mt < 2; ++mt)
        #pragma unroll
        for (int dt = 0; dt < 4; ++dt) oacc[mt][dt] = z4;

    bf16* Pw = &Pp[w][0][0];
    const bf16* kcbase = kb + (size_t)bh * 1024 * 64;
    const bf16* hcbase = htb + (size_t)b * 64 * 1024;

    for (int kc = 0; kc < 16; ++kc) {
        __syncthreads();
        {
            int row = t >> 2, c = (t & 3) << 4;
            const bf16* ksrc = kcbase + (size_t)(kc * 64 + row) * 64 + c;
            *(int4*)&Ks[row][c]     = *(const int4*)ksrc;
            *(int4*)&Ks[row][c + 8] = *(const int4*)(ksrc + 8);
            const bf16* hsrc = hcbase + (size_t)row * 1024 + kc * 64 + c;
            *(int4*)&Hts[row][c]     = *(const int4*)hsrc;
            *(int4*)&Hts[row][c + 8] = *(const int4*)(hsrc + 8);
        }
        float rb[2][2];
        #pragma unroll
        for (int mt = 0; mt < 2; ++mt) {
            bf16x2 rv = *(const bf16x2*)(rbp[mt] + kc * 2);
            rb[mt][0] = (float)rv[0]; rb[mt][1] = (float)rv[1];
        }
        __syncthreads();

        f32x4 sf[2][4];
        #pragma unroll
        for (int mt = 0; mt < 2; ++mt)
            #pragma unroll
            for (int kt = 0; kt < 4; ++kt) sf[mt][kt] = z4;
        #pragma unroll
        for (int kt = 0; kt < 4; ++kt) {
            bf16x8 aK0 = *(const bf16x8*)&Ks[kt * 16 + l15][quad * 8];
            bf16x8 aK1 = *(const bf16x8*)&Ks[kt * 16 + l15][32 + quad * 8];
            #pragma unroll
            for (int mt = 0; mt < 2; ++mt) {
                sf[mt][kt] = __builtin_amdgcn_mfma_f32_16x16x32_bf16(aK0, bq_[mt][0], sf[mt][kt], 0, 0, 0);
                sf[mt][kt] = __builtin_amdgcn_mfma_f32_16x16x32_bf16(aK1, bq_[mt][1], sf[mt][kt], 0, 0, 0);
            }
        }

        #pragma unroll
        for (int mt = 0; mt < 2; ++mt)
            #pragma unroll
            for (int kt = 0; kt < 4; ++kt) {
                float rbv = rb[mt][kt >> 1];
                ushort4 pk;
                float p0 = __expf(sf[mt][kt][0] + rbv + cbv[mt][kt & 1][0]);
                float p1 = __expf(sf[mt][kt][1] + rbv + cbv[mt][kt & 1][1]);
                float p2 = __expf(sf[mt][kt][2] + rbv + cbv[mt][kt & 1][2]);
                float p3 = __expf(sf[mt][kt][3] + rbv + cbv[mt][kt & 1][3]);
                lsum[mt] += (p0 + p1) + (p2 + p3);
                pk.x = f2bf_bits(p0); pk.y = f2bf_bits(p1);
                pk.z = f2bf_bits(p2); pk.w = f2bf_bits(p3);
                *(ushort4*)&Pw[(mt * 16 + l15) * 72 + kt * 16 + quad * 4] = pk;
            }

        bf16x8 bp[2][2];
        #pragma unroll
        for (int mt = 0; mt < 2; ++mt) {
            bp[mt][0] = *(const bf16x8*)&Pw[(mt * 16 + l15) * 72 + quad * 8];
            bp[mt][1] = *(const bf16x8*)&Pw[(mt * 16 + l15) * 72 + 32 + quad * 8];
        }
        #pragma unroll
        for (int dt = 0; dt < 4; ++dt) {
            bf16x8 aH0 = *(const bf16x8*)&Hts[dt * 16 + l15][quad * 8];
            bf16x8 aH1 = *(const bf16x8*)&Hts[dt * 16 + l15][32 + quad * 8];
            #pragma unroll
            for (int mt = 0; mt < 2; ++mt) {
                oacc[mt][dt] = __builtin_amdgcn_mfma_f32_16x16x32_bf16(aH0, bp[mt][0], oacc[mt][dt], 0, 0, 0);
                oacc[mt][dt] = __builtin_amdgcn_mfma_f32_16x16x32_bf16(aH1, bp[mt][1], oacc[mt][dt], 0, 0, 0);
            }
        }
    }

    float inv[2];
    #pragma unroll
    for (int mt = 0; mt < 2; ++mt) {
        float v = lsum[mt];
        v += __shfl_xor(v, 16);
        v += __shfl_xor(v, 32);
        inv[mt] = 1.0f / v;
    }
    #pragma unroll
    for (int mt = 0; mt < 2; ++mt) {
        int pos = q0 + w * 32 + mt * 16 + l15;
        bf16* mb = mixedb + ((size_t)b * 1024 + pos) * 512 + h * 64;
        #pragma unroll
        for (int dt = 0; dt < 4; ++dt) {
            ushort4 pk;
            pk.x = f2bf_bits(oacc[mt][dt][0] * inv[mt]);
            pk.y = f2bf_bits(oacc[mt][dt][1] * inv[mt]);
            pk.z = f2bf_bits(oacc[mt][dt][2] * inv[mt]);
            pk.w = f2bf_bits(oacc[mt][dt][3] * inv[mt]);
            *(ushort4*)(mb + dt * 16 + quad * 4) = pk;
        }
    }
}

// =====================================================================
// Kernel 4: output projection via MFMA — zero LDS, zero barriers (proven).
// grid 256 blocks (32 pos), block 256 (4 waves; wave w = col-tile).
// =====================================================================
__global__ __launch_bounds__(256)
void out_proj_kernel(const bf16* __restrict__ mixedb,
                     const bf16* __restrict__ Wvp, const float* __restrict__ bv,
                     float* __restrict__ out)
{
    const int t  = threadIdx.x;
    const int p0 = blockIdx.x * 32;
    const int w = t >> 6, ln = t & 63, l15 = ln & 15, quad = ln >> 4;

    float bvv = bv[w * 16 + l15];
    f32x4 acc[2] = {(f32x4){bvv, bvv, bvv, bvv}, (f32x4){bvv, bvv, bvv, bvv}};

    const bf16* arow0 = mixedb + (size_t)(p0 + l15) * 512 + quad * 8;
    const bf16* arow1 = mixedb + (size_t)(p0 + 16 + l15) * 512 + quad * 8;
    const bf16* bbase = Wvp + (size_t)w * 16 * 512 + l15 * 32 + quad * 8;

    #pragma unroll
    for (int kc = 0; kc < 16; ++kc) {
        bf16x8 a0 = *(const bf16x8*)(arow0 + kc * 32);
        bf16x8 a1 = *(const bf16x8*)(arow1 + kc * 32);
        bf16x8 bfrag = *(const bf16x8*)(bbase + kc * 512);
        acc[0] = __builtin_amdgcn_mfma_f32_16x16x32_bf16(a0, bfrag, acc[0], 0, 0, 0);
        acc[1] = __builtin_amdgcn_mfma_f32_16x16x32_bf16(a1, bfrag, acc[1], 0, 0, 0);
    }

    #pragma unroll
    for (int mt = 0; mt < 2; ++mt)
        #pragma unroll
        for (int r = 0; r < 4; ++r)
            out[(size_t)(p0 + mt * 16 + quad * 4 + r) * 64 + w * 16 + l15] = acc[mt][r];
}

// =====================================================================
extern "C" void kernel_launch(void* const* d_in, const int* in_sizes, int n_in,
                              void* d_out, int out_size, void* d_ws, size_t ws_size,
                              hipStream_t stream)
{
    const float* hid     = (const float*)d_in[0];
    const float* row_emb = (const float*)d_in[1];
    const float* col_emb = (const float*)d_in[2];
    const float* Wq      = (const float*)d_in[3];
    const float* bq      = (const float*)d_in[4];
    const float* Wk      = (const float*)d_in[5];
    const float* bk      = (const float*)d_in[6];
    const float* Wv      = (const float*)d_in[7];
    const float* bv      = (const float*)d_in[8];
    float* out = (float*)d_out;

    bf16* qb      = (bf16*)d_ws;
    bf16* kb      = qb + (size_t)64 * 1024 * 64;
    bf16* htb     = kb + (size_t)64 * 1024 * 64;
    bf16* rowbias = htb + (size_t)8 * 64 * 1024;
    bf16* colbias = rowbias + (size_t)64 * 1024 * 32;
    bf16* mixedb  = colbias + (size_t)64 * 1024 * 32;
    bf16* hb      = mixedb + (size_t)8 * 1024 * 512;
    bf16* Wqb     = hb + (size_t)8 * 1024 * 64;
    bf16* Wkb     = Wqb + (size_t)512 * 64;
    bf16* Wvp     = Wkb + (size_t)512 * 64;

    prep_kernel<<<128, 256, 0, stream>>>(hid, Wq, Wk, Wv, hb, htb, Wqb, Wkb, Wvp);
    qkproj_kernel<<<dim3(64, 4), 256, 0, stream>>>(hb, Wqb, bq, Wkb, bk, qb, kb);
    bias_kernel<<<dim3(64, 4), 256, 0, stream>>>(qb, row_emb, col_emb, rowbias, colbias);
    attn_kernel<<<dim3(8, 64), 256, 0, stream>>>(qb, kb, htb, rowbias, colbias, mixedb);
    out_proj_kernel<<<256, 256, 0, stream>>>(mixedb, Wvp, bv, out);
}